// Round 4
// baseline (403.023 us; speedup 1.0000x reference)
//
#include <hip/hip_runtime.h>

#define B_ 8
#define S_ 1024
#define C_ 512
#define H_ 8
#define D_ 64
#define P_ 16
#define SP_ 1040    // valid keys: S + P
#define SPAD_ 1088  // score-matrix row stride: 17*64
#define KSZ 3

typedef unsigned short u16;
typedef short bf16x8 __attribute__((ext_vector_type(8)));
typedef float f32x4 __attribute__((ext_vector_type(4)));

__device__ __forceinline__ float bf2f(u16 u) {
  return __uint_as_float(((unsigned int)u) << 16);
}
__device__ __forceinline__ u16 f2bf(float f) {
  unsigned int u = __float_as_uint(f);
  return (u16)((u + 0x7fffu + ((u >> 16) & 1u)) >> 16);
}
// Packed fp32->bf16 RNE convert: 1 instr for 2 values (same rounding as f2bf).
__device__ __forceinline__ unsigned int cvtpk(float lo, float hi) {
  unsigned int r;
  asm("v_cvt_pk_bf16_f32 %0, %1, %2" : "=v"(r) : "v"(lo), "v"(hi));
  return r;
}
// Raw v_exp_f32: computes 2^x in one instruction.
__device__ __forceinline__ float exp2v(float x) {
  float r;
  asm("v_exp_f32 %0, %1" : "=v"(r) : "v"(x));
  return r;
}
// Round 8 consecutive fp32 to bf16, packed as int4 (8 x u16).
__device__ __forceinline__ int4 pack8(const float* p) {
  int4 r;
  r.x = (int)cvtpk(p[0], p[1]);
  r.y = (int)cvtpk(p[2], p[3]);
  r.z = (int)cvtpk(p[4], p[5]);
  r.w = (int)cvtpk(p[6], p[7]);
  return r;
}

// Fused weight prep: W_fc cvt + conv1/conv2 repack (CO,CI,K)->[tap][co][ci].
__global__ void k_prep(const float* Wfc, u16* wfcb, const float* c1w, u16* w1t,
                       const float* c2w, u16* w2t) {
  int gid = blockIdx.x * 256 + threadIdx.x;  // 262144 + 2*786432 = 1835008
  if (gid < C_ * C_) {
    wfcb[gid] = f2bf(Wfc[gid]);
    return;
  }
  int r = gid - C_ * C_;
  const float* src = c1w;
  u16* dst = w1t;
  if (r >= C_ * C_ * KSZ) {
    r -= C_ * C_ * KSZ;
    src = c2w;
    dst = w2t;
  }
  int co = r / (C_ * KSZ);
  int rem = r - co * (C_ * KSZ);
  int ci = rem / KSZ;
  int tap = rem - ci * KSZ;
  dst[(size_t)tap * C_ * C_ + co * C_ + ci] = f2bf(src[r]);
}

// x fp32 -> bf16 once.
__global__ void k_xcvt(const float* x, u16* xb) {
  int gid = blockIdx.x * 256 + threadIdx.x;  // 524288 threads * 8 elems
  *(int4*)&xb[(size_t)gid * 8] = pack8(&x[(size_t)gid * 8]);
}

// QKV: per (mat, head) NT-GEMM via MFMA, M=B*S, N=64, K=64. bf16 out.
__global__ __launch_bounds__(256) void k_qkv(
    const u16* xb, const float* Wq, const float* Wk, const float* Wv,
    u16* qb, u16* kb, u16* vb) {
  __shared__ u16 As[64][72];
  __shared__ u16 Bs[64][72];
  int tid = threadIdx.x;
  int m0 = blockIdx.x * 64;
  int mat = blockIdx.y >> 3, h = blockIdx.y & 7;
  const float* W = (mat == 0) ? Wq : ((mat == 1) ? Wk : Wv);
  for (int u = tid; u < 512; u += 256) {
    int row = u >> 3, seg = u & 7;
    *(int4*)&As[row][seg * 8] =
        *(const int4*)&xb[(size_t)(m0 + row) * C_ + h * 64 + seg * 8];
    *(int4*)&Bs[row][seg * 8] = pack8(&W[row * 64 + seg * 8]);
  }
  __syncthreads();
  int w = tid >> 6, lane = tid & 63, qd = lane >> 4, l15 = lane & 15;
  f32x4 acc[4] = {};
  for (int ks = 0; ks < 2; ++ks) {
    bf16x8 a = *(const bf16x8*)&As[w * 16 + l15][ks * 32 + qd * 8];
    for (int t = 0; t < 4; ++t) {
      bf16x8 b = *(const bf16x8*)&Bs[t * 16 + l15][ks * 32 + qd * 8];
      acc[t] = __builtin_amdgcn_mfma_f32_16x16x32_bf16(a, b, acc[t], 0, 0, 0);
    }
  }
  for (int t = 0; t < 4; ++t)
    for (int r = 0; r < 4; ++r) {
      int m = m0 + w * 16 + qd * 4 + r;
      int n = m >> 10, s = m & 1023;
      int d = t * 16 + l15;
      u16 val = f2bf(acc[t][r]);
      if (mat == 0)
        qb[((size_t)(n * H_ + h) * S_ + s) * D_ + d] = val;
      else if (mat == 1)
        kb[((size_t)(n * H_ + h) * SPAD_ + s) * D_ + d] = val;
      else
        vb[((size_t)(n * H_ + h) * SPAD_ + s) * D_ + d] = val;
    }
}

// k/v rows [S, SPAD): prefix bf16 for p<P, zeros for the rest.
__global__ void k_prefix(const float* pk, const float* pv, u16* kb, u16* vb) {
  int gid = blockIdx.x * 256 + threadIdx.x;  // 64 nh * 64 p * 64 d
  int d = gid & 63;
  int t = gid >> 6;
  int p = t & 63, nh = t >> 6;
  int l = S_ + p;
  kb[((size_t)nh * SPAD_ + l) * D_ + d] = (p < P_) ? f2bf(pk[p * 64 + d]) : 0;
  vb[((size_t)nh * SPAD_ + l) * D_ + d] = (p < P_) ? f2bf(pv[p * 64 + d]) : 0;
}

// v^T: vtb[nh][d][l] = vb[nh][l][d] (bf16).
__global__ void k_vtrans(const u16* vb, u16* vtb) {
  __shared__ u16 tile[64][65];
  int nh = blockIdx.y, l0 = blockIdx.x * 64, tid = threadIdx.x;
  for (int u = tid; u < 4096; u += 256) {
    int r = u >> 6, c = u & 63;
    tile[r][c] = vb[((size_t)nh * SPAD_ + l0 + r) * D_ + c];
  }
  __syncthreads();
  for (int u = tid; u < 4096; u += 256) {
    int d = u >> 6, c2 = u & 63;
    vtb[((size_t)nh * D_ + d) * SPAD_ + l0 + c2] = tile[c2][d];
  }
}

// Energy: Sb[nh][q][l] = q.k via MFMA. R4: q-tile 128, acc[2][4] per wave.
__global__ __launch_bounds__(256) void k_energy(const u16* qb, const u16* kb,
                                                u16* Sb) {
  __shared__ u16 As[128][72];
  __shared__ u16 Bs[64][72];
  int tid = threadIdx.x;
  int l0 = blockIdx.x * 64, q0 = blockIdx.y * 128;
  int nh = blockIdx.z;  // n*H + h
  const u16* qsrc = qb + ((size_t)nh * S_ + q0) * D_;
  const u16* ksrc = kb + ((size_t)nh * SPAD_ + l0) * D_;
  for (int u = tid; u < 1024; u += 256) {
    int row = u >> 3, seg = u & 7;
    *(int4*)&As[row][seg * 8] = *(const int4*)&qsrc[row * 64 + seg * 8];
  }
  for (int u = tid; u < 512; u += 256) {
    int row = u >> 3, seg = u & 7;
    *(int4*)&Bs[row][seg * 8] = *(const int4*)&ksrc[row * 64 + seg * 8];
  }
  __syncthreads();
  int w = tid >> 6, lane = tid & 63, qd = lane >> 4, l15 = lane & 15;
  f32x4 acc[2][4] = {};
  for (int ks = 0; ks < 2; ++ks) {
    bf16x8 a0 = *(const bf16x8*)&As[w * 32 + l15][ks * 32 + qd * 8];
    bf16x8 a1 = *(const bf16x8*)&As[w * 32 + 16 + l15][ks * 32 + qd * 8];
    for (int t = 0; t < 4; ++t) {
      bf16x8 b = *(const bf16x8*)&Bs[t * 16 + l15][ks * 32 + qd * 8];
      acc[0][t] = __builtin_amdgcn_mfma_f32_16x16x32_bf16(a0, b, acc[0][t], 0, 0, 0);
      acc[1][t] = __builtin_amdgcn_mfma_f32_16x16x32_bf16(a1, b, acc[1][t], 0, 0, 0);
    }
  }
  for (int m = 0; m < 2; ++m)
    for (int t = 0; t < 4; ++t)
      for (int r = 0; r < 4; ++r) {
        int q = q0 + w * 32 + m * 16 + qd * 4 + r;
        int l = l0 + t * 16 + l15;
        Sb[((size_t)nh * S_ + q) * SPAD_ + l] = f2bf(acc[m][t][r]);
      }
}

// Per (n,q): premix (W_pre + folded ALiBi), softmax over l<SP, postmix.
// R4: exp2-domain softmax (v_exp_f32 directly); tail = the 16 valid prefix
// keys only (l in [1040,1088) is multiplied by zero V rows in k_av, so its
// Sb contents are dead -- no mask, no store there).
__global__ __launch_bounds__(256) void k_smx(u16* __restrict__ Sb,
                                             const float* __restrict__ Wpre,
                                             const float* __restrict__ Wpost) {
  __shared__ __align__(16) float red[8][36];  // [head][group], 32 groups
  __shared__ __align__(16) float fin[2][8];   // [0]=max, [1]=1/sum
  int tid = threadIdx.x;
  int n = blockIdx.x >> 10, q = blockIdx.x & 1023;
  const size_t hs = (size_t)S_ * SPAD_;
  u16* __restrict__ base = Sb + ((size_t)n * H_ * S_ + q) * SPAD_;
  // 1/sqrt(512) * log2(e): softmax in exp2 domain (exact same math).
  const float isc2 = 0.04419417382415922f * 1.4426950408889634f;

  int la = 4 * tid;
  bool hasB = (tid < 16);
  int lb = 1024 + tid;  // 16 valid prefix keys

  // Issue all global loads up front (MLP).
  uint2 ldA[8];
#pragma unroll
  for (int i = 0; i < 8; ++i) ldA[i] = *(const uint2*)(base + i * hs + la);
  u16 ldB[8];
  if (hasB) {
#pragma unroll
    for (int i = 0; i < 8; ++i) ldB[i] = base[i * hs + lb];
  }

  float bt[4];
#pragma unroll
  for (int j = 0; j < 4; ++j) bt[j] = -fabsf((float)(q - (la + j)));

  // ---------- premix chunk A (bias folded into inputs) ----------
  float eA[32];  // [o][4]
#pragma unroll
  for (int j = 0; j < 32; ++j) eA[j] = 0.f;
#pragma unroll
  for (int i = 0; i < 8; ++i) {
    const float ci = 1.0f / (float)(2 << i);  // 2^-(i+1), compile-time
    float x0 = bf2f((u16)(ldA[i].x & 0xffffu)) + bt[0] * ci;
    float x1 = bf2f((u16)(ldA[i].x >> 16)) + bt[1] * ci;
    float x2 = bf2f((u16)(ldA[i].y & 0xffffu)) + bt[2] * ci;
    float x3 = bf2f((u16)(ldA[i].y >> 16)) + bt[3] * ci;
#pragma unroll
    for (int o = 0; o < 8; ++o) {
      float wv = Wpre[o * 8 + i];  // uniform -> s_load, SGPR operand
      eA[4 * o + 0] += wv * x0;
      eA[4 * o + 1] += wv * x1;
      eA[4 * o + 2] += wv * x2;
      eA[4 * o + 3] += wv * x3;
    }
  }
#pragma unroll
  for (int j = 0; j < 32; ++j) eA[j] *= isc2;

  // ---------- premix tail: 16 prefix keys, 1 per thread, no bias ----------
  float eB[8];
  if (hasB) {
#pragma unroll
    for (int o = 0; o < 8; ++o) eB[o] = 0.f;
#pragma unroll
    for (int i = 0; i < 8; ++i) {
      float xi = bf2f(ldB[i]);
#pragma unroll
      for (int o = 0; o < 8; ++o) eB[o] += Wpre[o * 8 + i] * xi;
    }
#pragma unroll
    for (int o = 0; o < 8; ++o) eB[o] *= isc2;
  }

  // ---------- max: local -> 3-step butterfly -> LDS -> 64-thread ----------
  float ml[8];
#pragma unroll
  for (int o = 0; o < 8; ++o)
    ml[o] = fmaxf(fmaxf(eA[4 * o + 0], eA[4 * o + 1]),
                  fmaxf(eA[4 * o + 2], eA[4 * o + 3]));
  if (hasB) {
#pragma unroll
    for (int o = 0; o < 8; ++o) ml[o] = fmaxf(ml[o], eB[o]);
  }
#pragma unroll
  for (int o = 0; o < 8; ++o)
    for (int mm = 1; mm < 8; mm <<= 1)
      ml[o] = fmaxf(ml[o], __shfl_xor(ml[o], mm, 64));
  {
    int g = tid >> 3;
    if ((tid & 7) == 0) {
#pragma unroll
      for (int o = 0; o < 8; ++o) red[o][g] = ml[o];
    }
  }
  __syncthreads();
  if (tid < 64) {
    int o = tid >> 3, part = tid & 7;
    f32x4 pv = *(const f32x4*)&red[o][part * 4];
    float pm = fmaxf(fmaxf(pv[0], pv[1]), fmaxf(pv[2], pv[3]));
    for (int mm = 1; mm < 8; mm <<= 1) pm = fmaxf(pm, __shfl_xor(pm, mm, 64));
    if (part == 0) fin[0][o] = pm;
  }
  __syncthreads();

  // ---------- exp2 + sum (same two-level reduction) ----------
  f32x4 mlo = *(const f32x4*)&fin[0][0];
  f32x4 mhi = *(const f32x4*)&fin[0][4];
  float zl[8];
#pragma unroll
  for (int o = 0; o < 8; ++o) {
    float m = (o < 4) ? mlo[o & 3] : mhi[o & 3];
    float s = 0.f;
#pragma unroll
    for (int j = 0; j < 4; ++j) {
      eA[4 * o + j] = exp2v(eA[4 * o + j] - m);
      s += eA[4 * o + j];
    }
    zl[o] = s;
  }
  if (hasB) {
#pragma unroll
    for (int o = 0; o < 8; ++o) {
      float m = (o < 4) ? mlo[o & 3] : mhi[o & 3];
      eB[o] = exp2v(eB[o] - m);
      zl[o] += eB[o];
    }
  }
#pragma unroll
  for (int o = 0; o < 8; ++o)
    for (int mm = 1; mm < 8; mm <<= 1) zl[o] += __shfl_xor(zl[o], mm, 64);
  {
    int g = tid >> 3;
    if ((tid & 7) == 0) {
#pragma unroll
      for (int o = 0; o < 8; ++o) red[o][g] = zl[o];
    }
  }
  __syncthreads();
  if (tid < 64) {
    int o = tid >> 3, part = tid & 7;
    f32x4 pv = *(const f32x4*)&red[o][part * 4];
    float ps = (pv[0] + pv[1]) + (pv[2] + pv[3]);
    for (int mm = 1; mm < 8; mm <<= 1) ps += __shfl_xor(ps, mm, 64);
    if (part == 0) fin[1][o] = 1.0f / ps;
  }
  __syncthreads();

  f32x4 zlo = *(const f32x4*)&fin[1][0];
  f32x4 zhi = *(const f32x4*)&fin[1][4];

  // ---------- normalize + postmix + store, chunk A ----------
  {
#pragma unroll
    for (int o = 0; o < 8; ++o) {
      float iz = (o < 4) ? zlo[o & 3] : zhi[o & 3];
#pragma unroll
      for (int j = 0; j < 4; ++j) eA[4 * o + j] *= iz;
    }
#pragma unroll
    for (int o = 0; o < 8; ++o) {
      float p0 = 0.f, p1 = 0.f, p2 = 0.f, p3 = 0.f;
#pragma unroll
      for (int i = 0; i < 8; ++i) {
        float wv = Wpost[o * 8 + i];  // uniform -> s_load
        p0 += wv * eA[4 * i + 0];
        p1 += wv * eA[4 * i + 1];
        p2 += wv * eA[4 * i + 2];
        p3 += wv * eA[4 * i + 3];
      }
      uint2 u;
      u.x = cvtpk(p0, p1);
      u.y = cvtpk(p2, p3);
      *(uint2*)(base + o * hs + la) = u;
    }
  }
  // ---------- normalize + postmix + store, tail ----------
  if (hasB) {
#pragma unroll
    for (int o = 0; o < 8; ++o) {
      float iz = (o < 4) ? zlo[o & 3] : zhi[o & 3];
      eB[o] *= iz;
    }
#pragma unroll
    for (int o = 0; o < 8; ++o) {
      float p0 = 0.f;
#pragma unroll
      for (int i = 0; i < 8; ++i) p0 += Wpost[o * 8 + i] * eB[i];
      base[o * hs + lb] = f2bf(p0);
    }
  }
}

// AV: attb[n,q,h*64+d] = sum_l attn[nh,q,l]*vT[nh,d,l]. R4: q-tile 128.
__global__ __launch_bounds__(256) void k_av(const u16* Sb, const u16* vtb,
                                            u16* attb) {
  __shared__ u16 As[128][72];
  __shared__ u16 Bs[64][72];
  int tid = threadIdx.x;
  int q0 = blockIdx.x * 128;
  int nh = blockIdx.y;
  int n = nh >> 3, h = nh & 7;
  const u16* Ab = Sb + ((size_t)nh * S_ + q0) * SPAD_;
  const u16* Bb = vtb + (size_t)nh * D_ * SPAD_;
  int w = tid >> 6, lane = tid & 63, qd = lane >> 4, l15 = lane & 15;
  f32x4 acc[2][4] = {};
  for (int ks = 0; ks < 17; ++ks) {
    int k0 = ks * 64;
    __syncthreads();
    for (int u = tid; u < 1024; u += 256) {
      int row = u >> 3, seg = u & 7;
      *(int4*)&As[row][seg * 8] =
          *(const int4*)&Ab[(size_t)row * SPAD_ + k0 + seg * 8];
    }
    for (int u = tid; u < 512; u += 256) {
      int row = u >> 3, seg = u & 7;
      *(int4*)&Bs[row][seg * 8] =
          *(const int4*)&Bb[(size_t)row * SPAD_ + k0 + seg * 8];
    }
    __syncthreads();
    for (int k2 = 0; k2 < 2; ++k2) {
      bf16x8 a0 = *(const bf16x8*)&As[w * 32 + l15][k2 * 32 + qd * 8];
      bf16x8 a1 = *(const bf16x8*)&As[w * 32 + 16 + l15][k2 * 32 + qd * 8];
      for (int t = 0; t < 4; ++t) {
        bf16x8 b = *(const bf16x8*)&Bs[t * 16 + l15][k2 * 32 + qd * 8];
        acc[0][t] = __builtin_amdgcn_mfma_f32_16x16x32_bf16(a0, b, acc[0][t], 0, 0, 0);
        acc[1][t] = __builtin_amdgcn_mfma_f32_16x16x32_bf16(a1, b, acc[1][t], 0, 0, 0);
      }
    }
  }
  for (int m = 0; m < 2; ++m)
    for (int t = 0; t < 4; ++t)
      for (int r = 0; r < 4; ++r) {
        int q = q0 + w * 32 + m * 16 + qd * 4 + r;
        int c = h * 64 + t * 16 + l15;
        attb[((size_t)(n * S_ + q)) * C_ + c] = f2bf(acc[m][t][r]);
      }
}

// FC + residual: hp = x + att @ Wfc^T + bfc (fp32 out). R4: m-tile 128.
__global__ __launch_bounds__(256) void k_fc(const u16* attb, const u16* Wfcb,
                                            const float* bfc, const float* x,
                                            float* hp) {
  __shared__ u16 As[128][72];
  __shared__ u16 Bs[64][72];
  int tid = threadIdx.x;
  int m0 = blockIdx.x * 128, n0 = blockIdx.y * 64;
  int w = tid >> 6, lane = tid & 63, qd = lane >> 4, l15 = lane & 15;
  f32x4 acc[2][4] = {};
  for (int ks = 0; ks < 8; ++ks) {
    int k0 = ks * 64;
    __syncthreads();
    for (int u = tid; u < 1024; u += 256) {
      int row = u >> 3, seg = u & 7;
      *(int4*)&As[row][seg * 8] =
          *(const int4*)&attb[(size_t)(m0 + row) * C_ + k0 + seg * 8];
    }
    for (int u = tid; u < 512; u += 256) {
      int row = u >> 3, seg = u & 7;
      *(int4*)&Bs[row][seg * 8] =
          *(const int4*)&Wfcb[(size_t)(n0 + row) * C_ + k0 + seg * 8];
    }
    __syncthreads();
    for (int k2 = 0; k2 < 2; ++k2) {
      bf16x8 a0 = *(const bf16x8*)&As[w * 32 + l15][k2 * 32 + qd * 8];
      bf16x8 a1 = *(const bf16x8*)&As[w * 32 + 16 + l15][k2 * 32 + qd * 8];
      for (int t = 0; t < 4; ++t) {
        bf16x8 b = *(const bf16x8*)&Bs[t * 16 + l15][k2 * 32 + qd * 8];
        acc[0][t] = __builtin_amdgcn_mfma_f32_16x16x32_bf16(a0, b, acc[0][t], 0, 0, 0);
        acc[1][t] = __builtin_amdgcn_mfma_f32_16x16x32_bf16(a1, b, acc[1][t], 0, 0, 0);
      }
    }
  }
  for (int m = 0; m < 2; ++m)
    for (int t = 0; t < 4; ++t)
      for (int r = 0; r < 4; ++r) {
        int mm = m0 + w * 32 + m * 16 + qd * 4 + r;
        int c = n0 + t * 16 + l15;
        hp[(size_t)mm * C_ + c] = acc[m][t][r] + bfc[c] + x[(size_t)mm * C_ + c];
      }
}

// LayerNorm over C per row; fp32 in, bf16 out.
__global__ __launch_bounds__(512) void k_ln(const float* hp, const float* g,
                                            const float* b, u16* hb) {
  __shared__ float r1[8], r2[8];
  int row = blockIdx.x, tid = threadIdx.x;
  int w = tid >> 6, lane = tid & 63;
  float v = hp[(size_t)row * C_ + tid];
  float s1 = v, s2 = v * v;
  for (int m = 1; m < 64; m <<= 1) {
    s1 += __shfl_xor(s1, m, 64);
    s2 += __shfl_xor(s2, m, 64);
  }
  if (lane == 0) {
    r1[w] = s1;
    r2[w] = s2;
  }
  __syncthreads();
  float t1 = 0.f, t2 = 0.f;
  for (int i = 0; i < 8; ++i) {
    t1 += r1[i];
    t2 += r2[i];
  }
  float mu = t1 * (1.0f / C_);
  float var = t2 * (1.0f / C_) - mu * mu;
  float o = (v - mu) * rsqrtf(var + 1e-5f) * g[tid] + b[tid];
  hb[(size_t)row * C_ + tid] = f2bf(o);
}

// Causal conv (K=3, left pad 2) as 3 accumulated MFMA NT-GEMMs.
// R4: s-tile 128 (+2 halo), acc[2][4] per wave, K-step 64.
// mode 0: out = relu(acc+bias) -> outb bf16
// mode 1: out = relu(relu(acc+bias)+res) -> outf fp32
__global__ __launch_bounds__(256) void k_conv(const u16* in, const u16* wt,
                                              const float* bias,
                                              const u16* res, u16* outb,
                                              float* outf, int mode) {
  __shared__ u16 As[130][72];
  __shared__ u16 Bs[3][64][72];
  int tid = threadIdx.x;
  int m0 = blockIdx.x * 128, n0 = blockIdx.y * 64;
  int n = m0 >> 10, s0 = m0 & 1023;
  int w = tid >> 6, lane = tid & 63, qd = lane >> 4, l15 = lane & 15;
  f32x4 acc[2][4] = {};
  for (int ks = 0; ks < 8; ++ks) {
    int k0 = ks * 64;
    __syncthreads();
    for (int u = tid; u < 1040; u += 256) {
      int row = u >> 3, seg = u & 7;
      int s = s0 + row - 2;
      int4 pa;
      pa.x = pa.y = pa.z = pa.w = 0;
      if (s >= 0)
        pa = *(const int4*)&in[((size_t)(n * S_ + s)) * C_ + k0 + seg * 8];
      *(int4*)&As[row][seg * 8] = pa;
    }
    for (int u = tid; u < 1536; u += 256) {
      int tap = u >> 9, rr = (u >> 3) & 63, seg = u & 7;
      *(int4*)&Bs[tap][rr][seg * 8] = *(const int4*)&wt[
          (size_t)tap * C_ * C_ + (size_t)(n0 + rr) * C_ + k0 + seg * 8];
    }
    __syncthreads();
    for (int k2 = 0; k2 < 2; ++k2) {
      for (int tap = 0; tap < 3; ++tap) {
        bf16x8 a0 = *(const bf16x8*)&As[w * 32 + l15 + tap][k2 * 32 + qd * 8];
        bf16x8 a1 =
            *(const bf16x8*)&As[w * 32 + 16 + l15 + tap][k2 * 32 + qd * 8];
        for (int t = 0; t < 4; ++t) {
          bf16x8 b = *(const bf16x8*)&Bs[tap][t * 16 + l15][k2 * 32 + qd * 8];
          acc[0][t] =
              __builtin_amdgcn_mfma_f32_16x16x32_bf16(a0, b, acc[0][t], 0, 0, 0);
          acc[1][t] =
              __builtin_amdgcn_mfma_f32_16x16x32_bf16(a1, b, acc[1][t], 0, 0, 0);
        }
      }
    }
  }
  for (int m = 0; m < 2; ++m)
    for (int t = 0; t < 4; ++t)
      for (int r = 0; r < 4; ++r) {
        int s = s0 + w * 32 + m * 16 + qd * 4 + r;
        int c = n0 + t * 16 + l15;
        float val = fmaxf(acc[m][t][r] + bias[c], 0.0f);
        size_t idx = ((size_t)(n * S_ + s)) * C_ + c;
        if (mode) {
          val = fmaxf(val + bf2f(res[idx]), 0.0f);
          outf[idx] = val;
        } else {
          outb[idx] = f2bf(val);
        }
      }
}

extern "C" void kernel_launch(void* const* d_in, const int* in_sizes, int n_in,
                              void* d_out, int out_size, void* d_ws,
                              size_t ws_size, hipStream_t stream) {
  int o = (in_sizes[1] == D_ * D_) ? 1 : 2;  // dict vs signature order
  const float* x = (const float*)d_in[0];
  const float* Wq = (const float*)d_in[o + 0];
  const float* Wk = (const float*)d_in[o + 1];
  const float* Wv = (const float*)d_in[o + 2];
  const float* Wfc = (const float*)d_in[o + 3];
  const float* bfc = (const float*)d_in[o + 4];
  const float* Wpre = (const float*)d_in[o + 5];
  const float* Wpost = (const float*)d_in[o + 6];
  const float* pk = (const float*)d_in[o + 7];
  const float* pv = (const float*)d_in[o + 8];
  const float* lng = (const float*)d_in[o + 9];
  const float* lnb = (const float*)d_in[o + 10];
  const float* c1w = (const float*)d_in[o + 11];
  const float* c1b = (const float*)d_in[o + 12];
  const float* c2w = (const float*)d_in[o + 13];
  const float* c2b = (const float*)d_in[o + 14];
  float* out = (float*)d_out;

  // Workspace ~232 MB (ws_size = 256 MiB per the harness poison fill).
  char* ws = (char*)d_ws;
  size_t off = 0;
  u16* qb = (u16*)(ws + off);   off += (size_t)B_ * H_ * S_ * D_ * 2;
  u16* kb = (u16*)(ws + off);   off += (size_t)B_ * H_ * SPAD_ * D_ * 2;
  u16* vb = (u16*)(ws + off);   off += (size_t)B_ * H_ * SPAD_ * D_ * 2;
  u16* vtb = (u16*)(ws + off);  off += (size_t)B_ * H_ * D_ * SPAD_ * 2;
  u16* Sb = (u16*)(ws + off);   off += (size_t)B_ * H_ * S_ * SPAD_ * 2;  // 142.6MB
  u16* attb = (u16*)(ws + off); off += (size_t)B_ * S_ * C_ * 2;
  float* hp = (float*)(ws + off); off += (size_t)B_ * S_ * C_ * 4;
  u16* hb = (u16*)(ws + off);   off += (size_t)B_ * S_ * C_ * 2;
  u16* o1b = (u16*)(ws + off);  off += (size_t)B_ * S_ * C_ * 2;
  u16* wfcb = (u16*)(ws + off); off += (size_t)C_ * C_ * 2;
  u16* w1t = (u16*)(ws + off);  off += (size_t)KSZ * C_ * C_ * 2;
  u16* w2t = (u16*)(ws + off);  off += (size_t)KSZ * C_ * C_ * 2;
  u16* xb = (u16*)(ws + off);   off += (size_t)B_ * S_ * C_ * 2;

  k_prep<<<7168, 256, 0, stream>>>(Wfc, wfcb, c1w, w1t, c2w, w2t);
  k_xcvt<<<2048, 256, 0, stream>>>(x, xb);
  k_qkv<<<dim3(128, 24), 256, 0, stream>>>(xb, Wq, Wk, Wv, qb, kb, vb);
  k_prefix<<<1024, 256, 0, stream>>>(pk, pv, kb, vb);
  k_vtrans<<<dim3(17, 64), 256, 0, stream>>>(vb, vtb);
  k_energy<<<dim3(17, 8, 64), 256, 0, stream>>>(qb, kb, Sb);
  k_smx<<<8192, 256, 0, stream>>>(Sb, Wpre, Wpost);
  k_av<<<dim3(8, 64), 256, 0, stream>>>(Sb, vtb, attb);
  k_fc<<<dim3(64, 8), 256, 0, stream>>>(attb, wfcb, bfc, x, hp);
  k_ln<<<8192, 512, 0, stream>>>(hp, lng, lnb, hb);
  k_conv<<<dim3(64, 8), 256, 0, stream>>>(hb, w1t, c1b, (const u16*)0, o1b,
                                          (float*)0, 0);
  k_conv<<<dim3(64, 8), 256, 0, stream>>>(o1b, w2t, c2b, hb, (u16*)0, out, 1);
}

// Round 5
// 341.192 us; speedup vs baseline: 1.1812x; 1.1812x over previous
//
#include <hip/hip_runtime.h>

#define B_ 8
#define S_ 1024
#define C_ 512
#define H_ 8
#define D_ 64
#define P_ 16
#define SP_ 1040    // valid keys: S + P
#define SPAD_ 1088  // score-matrix row stride: 17*64
#define KSZ 3

typedef unsigned short u16;
typedef short bf16x8 __attribute__((ext_vector_type(8)));
typedef float f32x4 __attribute__((ext_vector_type(4)));

__device__ __forceinline__ float bf2f(u16 u) {
  return __uint_as_float(((unsigned int)u) << 16);
}
__device__ __forceinline__ u16 f2bf(float f) {
  unsigned int u = __float_as_uint(f);
  return (u16)((u + 0x7fffu + ((u >> 16) & 1u)) >> 16);
}
// Packed fp32->bf16 RNE convert: 1 instr for 2 values (same rounding as f2bf).
__device__ __forceinline__ unsigned int cvtpk(float lo, float hi) {
  unsigned int r;
  asm("v_cvt_pk_bf16_f32 %0, %1, %2" : "=v"(r) : "v"(lo), "v"(hi));
  return r;
}
// Raw v_exp_f32: computes 2^x in one instruction.
__device__ __forceinline__ float exp2v(float x) {
  float r;
  asm("v_exp_f32 %0, %1" : "=v"(r) : "v"(x));
  return r;
}
// Round 8 consecutive fp32 to bf16, packed as int4 (8 x u16).
__device__ __forceinline__ int4 pack8(const float* p) {
  int4 r;
  r.x = (int)cvtpk(p[0], p[1]);
  r.y = (int)cvtpk(p[2], p[3]);
  r.z = (int)cvtpk(p[4], p[5]);
  r.w = (int)cvtpk(p[6], p[7]);
  return r;
}

// Fused weight prep: W_fc cvt + conv1/conv2 repack (CO,CI,K)->[tap][co][ci].
__global__ void k_prep(const float* Wfc, u16* wfcb, const float* c1w, u16* w1t,
                       const float* c2w, u16* w2t) {
  int gid = blockIdx.x * 256 + threadIdx.x;  // 262144 + 2*786432 = 1835008
  if (gid < C_ * C_) {
    wfcb[gid] = f2bf(Wfc[gid]);
    return;
  }
  int r = gid - C_ * C_;
  const float* src = c1w;
  u16* dst = w1t;
  if (r >= C_ * C_ * KSZ) {
    r -= C_ * C_ * KSZ;
    src = c2w;
    dst = w2t;
  }
  int co = r / (C_ * KSZ);
  int rem = r - co * (C_ * KSZ);
  int ci = rem / KSZ;
  int tap = rem - ci * KSZ;
  dst[(size_t)tap * C_ * C_ + co * C_ + ci] = f2bf(src[r]);
}

// x fp32 -> bf16 once.
__global__ void k_xcvt(const float* x, u16* xb) {
  int gid = blockIdx.x * 256 + threadIdx.x;  // 524288 threads * 8 elems
  *(int4*)&xb[(size_t)gid * 8] = pack8(&x[(size_t)gid * 8]);
}

// QKV: per (mat, head) NT-GEMM via MFMA, M=B*S, N=64, K=64. bf16 out.
// R5: XCD-chunked block swizzle; chunk shares the x row-tile.
__global__ __launch_bounds__(256) void k_qkv(
    const u16* xb, const float* Wq, const float* Wk, const float* Wv,
    u16* qb, u16* kb, u16* vb) {
  __shared__ u16 As[64][72];
  __shared__ u16 Bs[64][72];
  int tid = threadIdx.x;
  int lin = blockIdx.x + 128 * blockIdx.y;        // 3072 blocks
  lin = (lin & 7) * (3072 >> 3) + (lin >> 3);     // bijective XCD chunking
  int m0 = (lin / 24) * 64;
  int yy = lin % 24;
  int mat = yy >> 3, h = yy & 7;
  const float* W = (mat == 0) ? Wq : ((mat == 1) ? Wk : Wv);
  for (int u = tid; u < 512; u += 256) {
    int row = u >> 3, seg = u & 7;
    *(int4*)&As[row][seg * 8] =
        *(const int4*)&xb[(size_t)(m0 + row) * C_ + h * 64 + seg * 8];
    *(int4*)&Bs[row][seg * 8] = pack8(&W[row * 64 + seg * 8]);
  }
  __syncthreads();
  int w = tid >> 6, lane = tid & 63, qd = lane >> 4, l15 = lane & 15;
  f32x4 acc[4] = {};
  for (int ks = 0; ks < 2; ++ks) {
    bf16x8 a = *(const bf16x8*)&As[w * 16 + l15][ks * 32 + qd * 8];
    for (int t = 0; t < 4; ++t) {
      bf16x8 b = *(const bf16x8*)&Bs[t * 16 + l15][ks * 32 + qd * 8];
      acc[t] = __builtin_amdgcn_mfma_f32_16x16x32_bf16(a, b, acc[t], 0, 0, 0);
    }
  }
  for (int t = 0; t < 4; ++t)
    for (int r = 0; r < 4; ++r) {
      int m = m0 + w * 16 + qd * 4 + r;
      int n = m >> 10, s = m & 1023;
      int d = t * 16 + l15;
      u16 val = f2bf(acc[t][r]);
      if (mat == 0)
        qb[((size_t)(n * H_ + h) * S_ + s) * D_ + d] = val;
      else if (mat == 1)
        kb[((size_t)(n * H_ + h) * SPAD_ + s) * D_ + d] = val;
      else
        vb[((size_t)(n * H_ + h) * SPAD_ + s) * D_ + d] = val;
    }
}

// k/v rows [S, SPAD): prefix bf16 for p<P, zeros for the rest.
__global__ void k_prefix(const float* pk, const float* pv, u16* kb, u16* vb) {
  int gid = blockIdx.x * 256 + threadIdx.x;  // 64 nh * 64 p * 64 d
  int d = gid & 63;
  int t = gid >> 6;
  int p = t & 63, nh = t >> 6;
  int l = S_ + p;
  kb[((size_t)nh * SPAD_ + l) * D_ + d] = (p < P_) ? f2bf(pk[p * 64 + d]) : 0;
  vb[((size_t)nh * SPAD_ + l) * D_ + d] = (p < P_) ? f2bf(pv[p * 64 + d]) : 0;
}

// v^T: vtb[nh][d][l] = vb[nh][l][d] (bf16).
__global__ void k_vtrans(const u16* vb, u16* vtb) {
  __shared__ u16 tile[64][65];
  int nh = blockIdx.y, l0 = blockIdx.x * 64, tid = threadIdx.x;
  for (int u = tid; u < 4096; u += 256) {
    int r = u >> 6, c = u & 63;
    tile[r][c] = vb[((size_t)nh * SPAD_ + l0 + r) * D_ + c];
  }
  __syncthreads();
  for (int u = tid; u < 4096; u += 256) {
    int d = u >> 6, c2 = u & 63;
    vtb[((size_t)nh * D_ + d) * SPAD_ + l0 + c2] = tile[c2][d];
  }
}

// Energy: Sb[nh][q][l] = q.k via MFMA (R3 64-tile). R5: XCD swizzle; a chunk
// walks the 17 l-tiles of one (q-tile, nh) -> Q-tile stays in that XCD's L2.
__global__ __launch_bounds__(256) void k_energy(const u16* qb, const u16* kb,
                                                u16* Sb) {
  __shared__ u16 As[64][72];
  __shared__ u16 Bs[64][72];
  int tid = threadIdx.x;
  int lin = blockIdx.x + 17 * (blockIdx.y + 16 * blockIdx.z);  // 17408
  lin = (lin & 7) * (17408 >> 3) + (lin >> 3);
  int l0 = (lin % 17) * 64;
  int t0 = lin / 17;
  int q0 = (t0 & 15) * 64;
  int nh = t0 >> 4;  // n*H + h
  const u16* qsrc = qb + ((size_t)nh * S_ + q0) * D_;
  const u16* ksrc = kb + ((size_t)nh * SPAD_ + l0) * D_;
  for (int u = tid; u < 512; u += 256) {
    int row = u >> 3, seg = u & 7;
    *(int4*)&As[row][seg * 8] = *(const int4*)&qsrc[row * 64 + seg * 8];
    *(int4*)&Bs[row][seg * 8] = *(const int4*)&ksrc[row * 64 + seg * 8];
  }
  __syncthreads();
  int w = tid >> 6, lane = tid & 63, qd = lane >> 4, l15 = lane & 15;
  f32x4 acc[4] = {};
  for (int ks = 0; ks < 2; ++ks) {
    bf16x8 a = *(const bf16x8*)&As[w * 16 + l15][ks * 32 + qd * 8];
    for (int t = 0; t < 4; ++t) {
      bf16x8 b = *(const bf16x8*)&Bs[t * 16 + l15][ks * 32 + qd * 8];
      acc[t] = __builtin_amdgcn_mfma_f32_16x16x32_bf16(a, b, acc[t], 0, 0, 0);
    }
  }
  for (int t = 0; t < 4; ++t)
    for (int r = 0; r < 4; ++r) {
      int q = q0 + w * 16 + qd * 4 + r;
      int l = l0 + t * 16 + l15;
      Sb[((size_t)nh * S_ + q) * SPAD_ + l] = f2bf(acc[t][r]);
    }
}

// Per (n,q): premix (W_pre + folded ALiBi), softmax over l<SP, postmix.
// R4 version: exp2-domain softmax; tail = 16 valid prefix keys only
// (l in [1040,1088) multiplies zero V rows in k_av -> dead, not stored).
__global__ __launch_bounds__(256) void k_smx(u16* __restrict__ Sb,
                                             const float* __restrict__ Wpre,
                                             const float* __restrict__ Wpost) {
  __shared__ __align__(16) float red[8][36];  // [head][group], 32 groups
  __shared__ __align__(16) float fin[2][8];   // [0]=max, [1]=1/sum
  int tid = threadIdx.x;
  int n = blockIdx.x >> 10, q = blockIdx.x & 1023;
  const size_t hs = (size_t)S_ * SPAD_;
  u16* __restrict__ base = Sb + ((size_t)n * H_ * S_ + q) * SPAD_;
  // 1/sqrt(512) * log2(e): softmax in exp2 domain (exact same math).
  const float isc2 = 0.04419417382415922f * 1.4426950408889634f;

  int la = 4 * tid;
  bool hasB = (tid < 16);
  int lb = 1024 + tid;  // 16 valid prefix keys

  // Issue all global loads up front (MLP).
  uint2 ldA[8];
#pragma unroll
  for (int i = 0; i < 8; ++i) ldA[i] = *(const uint2*)(base + i * hs + la);
  u16 ldB[8];
  if (hasB) {
#pragma unroll
    for (int i = 0; i < 8; ++i) ldB[i] = base[i * hs + lb];
  }

  float bt[4];
#pragma unroll
  for (int j = 0; j < 4; ++j) bt[j] = -fabsf((float)(q - (la + j)));

  // ---------- premix chunk A (bias folded into inputs) ----------
  float eA[32];  // [o][4]
#pragma unroll
  for (int j = 0; j < 32; ++j) eA[j] = 0.f;
#pragma unroll
  for (int i = 0; i < 8; ++i) {
    const float ci = 1.0f / (float)(2 << i);  // 2^-(i+1), compile-time
    float x0 = bf2f((u16)(ldA[i].x & 0xffffu)) + bt[0] * ci;
    float x1 = bf2f((u16)(ldA[i].x >> 16)) + bt[1] * ci;
    float x2 = bf2f((u16)(ldA[i].y & 0xffffu)) + bt[2] * ci;
    float x3 = bf2f((u16)(ldA[i].y >> 16)) + bt[3] * ci;
#pragma unroll
    for (int o = 0; o < 8; ++o) {
      float wv = Wpre[o * 8 + i];  // uniform -> s_load, SGPR operand
      eA[4 * o + 0] += wv * x0;
      eA[4 * o + 1] += wv * x1;
      eA[4 * o + 2] += wv * x2;
      eA[4 * o + 3] += wv * x3;
    }
  }
#pragma unroll
  for (int j = 0; j < 32; ++j) eA[j] *= isc2;

  // ---------- premix tail: 16 prefix keys, 1 per thread, no bias ----------
  float eB[8];
  if (hasB) {
#pragma unroll
    for (int o = 0; o < 8; ++o) eB[o] = 0.f;
#pragma unroll
    for (int i = 0; i < 8; ++i) {
      float xi = bf2f(ldB[i]);
#pragma unroll
      for (int o = 0; o < 8; ++o) eB[o] += Wpre[o * 8 + i] * xi;
    }
#pragma unroll
    for (int o = 0; o < 8; ++o) eB[o] *= isc2;
  }

  // ---------- max: local -> 3-step butterfly -> LDS -> 64-thread ----------
  float ml[8];
#pragma unroll
  for (int o = 0; o < 8; ++o)
    ml[o] = fmaxf(fmaxf(eA[4 * o + 0], eA[4 * o + 1]),
                  fmaxf(eA[4 * o + 2], eA[4 * o + 3]));
  if (hasB) {
#pragma unroll
    for (int o = 0; o < 8; ++o) ml[o] = fmaxf(ml[o], eB[o]);
  }
#pragma unroll
  for (int o = 0; o < 8; ++o)
    for (int mm = 1; mm < 8; mm <<= 1)
      ml[o] = fmaxf(ml[o], __shfl_xor(ml[o], mm, 64));
  {
    int g = tid >> 3;
    if ((tid & 7) == 0) {
#pragma unroll
      for (int o = 0; o < 8; ++o) red[o][g] = ml[o];
    }
  }
  __syncthreads();
  if (tid < 64) {
    int o = tid >> 3, part = tid & 7;
    f32x4 pv = *(const f32x4*)&red[o][part * 4];
    float pm = fmaxf(fmaxf(pv[0], pv[1]), fmaxf(pv[2], pv[3]));
    for (int mm = 1; mm < 8; mm <<= 1) pm = fmaxf(pm, __shfl_xor(pm, mm, 64));
    if (part == 0) fin[0][o] = pm;
  }
  __syncthreads();

  // ---------- exp2 + sum (same two-level reduction) ----------
  f32x4 mlo = *(const f32x4*)&fin[0][0];
  f32x4 mhi = *(const f32x4*)&fin[0][4];
  float zl[8];
#pragma unroll
  for (int o = 0; o < 8; ++o) {
    float m = (o < 4) ? mlo[o & 3] : mhi[o & 3];
    float s = 0.f;
#pragma unroll
    for (int j = 0; j < 4; ++j) {
      eA[4 * o + j] = exp2v(eA[4 * o + j] - m);
      s += eA[4 * o + j];
    }
    zl[o] = s;
  }
  if (hasB) {
#pragma unroll
    for (int o = 0; o < 8; ++o) {
      float m = (o < 4) ? mlo[o & 3] : mhi[o & 3];
      eB[o] = exp2v(eB[o] - m);
      zl[o] += eB[o];
    }
  }
#pragma unroll
  for (int o = 0; o < 8; ++o)
    for (int mm = 1; mm < 8; mm <<= 1) zl[o] += __shfl_xor(zl[o], mm, 64);
  {
    int g = tid >> 3;
    if ((tid & 7) == 0) {
#pragma unroll
      for (int o = 0; o < 8; ++o) red[o][g] = zl[o];
    }
  }
  __syncthreads();
  if (tid < 64) {
    int o = tid >> 3, part = tid & 7;
    f32x4 pv = *(const f32x4*)&red[o][part * 4];
    float ps = (pv[0] + pv[1]) + (pv[2] + pv[3]);
    for (int mm = 1; mm < 8; mm <<= 1) ps += __shfl_xor(ps, mm, 64);
    if (part == 0) fin[1][o] = 1.0f / ps;
  }
  __syncthreads();

  f32x4 zlo = *(const f32x4*)&fin[1][0];
  f32x4 zhi = *(const f32x4*)&fin[1][4];

  // ---------- normalize + postmix + store, chunk A ----------
  {
#pragma unroll
    for (int o = 0; o < 8; ++o) {
      float iz = (o < 4) ? zlo[o & 3] : zhi[o & 3];
#pragma unroll
      for (int j = 0; j < 4; ++j) eA[4 * o + j] *= iz;
    }
#pragma unroll
    for (int o = 0; o < 8; ++o) {
      float p0 = 0.f, p1 = 0.f, p2 = 0.f, p3 = 0.f;
#pragma unroll
      for (int i = 0; i < 8; ++i) {
        float wv = Wpost[o * 8 + i];  // uniform -> s_load
        p0 += wv * eA[4 * i + 0];
        p1 += wv * eA[4 * i + 1];
        p2 += wv * eA[4 * i + 2];
        p3 += wv * eA[4 * i + 3];
      }
      uint2 u;
      u.x = cvtpk(p0, p1);
      u.y = cvtpk(p2, p3);
      *(uint2*)(base + o * hs + la) = u;
    }
  }
  // ---------- normalize + postmix + store, tail ----------
  if (hasB) {
#pragma unroll
    for (int o = 0; o < 8; ++o) {
      float iz = (o < 4) ? zlo[o & 3] : zhi[o & 3];
      eB[o] *= iz;
    }
#pragma unroll
    for (int o = 0; o < 8; ++o) {
      float p0 = 0.f;
#pragma unroll
      for (int i = 0; i < 8; ++i) p0 += Wpost[o * 8 + i] * eB[i];
      base[o * hs + lb] = f2bf(p0);
    }
  }
}

// AV: attb = attn @ vT (R3 64-tile, K-step 64). R5: XCD swizzle; a chunk
// walks q-tiles of one nh -> vT[nh] stays in that XCD's L2.
__global__ __launch_bounds__(256) void k_av(const u16* Sb, const u16* vtb,
                                            u16* attb) {
  __shared__ u16 As[64][72];
  __shared__ u16 Bs[64][72];
  int tid = threadIdx.x;
  int lin = blockIdx.x + 16 * blockIdx.y;  // 1024 blocks
  lin = (lin & 7) * (1024 >> 3) + (lin >> 3);
  int q0 = (lin & 15) * 64;
  int nh = lin >> 4;
  int n = nh >> 3, h = nh & 7;
  const u16* Ab = Sb + ((size_t)nh * S_ + q0) * SPAD_;
  const u16* Bb = vtb + (size_t)nh * D_ * SPAD_;
  int w = tid >> 6, lane = tid & 63, qd = lane >> 4, l15 = lane & 15;
  f32x4 acc[4] = {};
  for (int ks = 0; ks < 17; ++ks) {
    int k0 = ks * 64;
    __syncthreads();
    for (int u = tid; u < 512; u += 256) {
      int row = u >> 3, seg = u & 7;
      *(int4*)&As[row][seg * 8] =
          *(const int4*)&Ab[(size_t)row * SPAD_ + k0 + seg * 8];
      *(int4*)&Bs[row][seg * 8] =
          *(const int4*)&Bb[(size_t)row * SPAD_ + k0 + seg * 8];
    }
    __syncthreads();
    for (int k2 = 0; k2 < 2; ++k2) {
      bf16x8 a = *(const bf16x8*)&As[w * 16 + l15][k2 * 32 + qd * 8];
      for (int t = 0; t < 4; ++t) {
        bf16x8 b = *(const bf16x8*)&Bs[t * 16 + l15][k2 * 32 + qd * 8];
        acc[t] = __builtin_amdgcn_mfma_f32_16x16x32_bf16(a, b, acc[t], 0, 0, 0);
      }
    }
  }
  for (int t = 0; t < 4; ++t)
    for (int r = 0; r < 4; ++r) {
      int q = q0 + w * 16 + qd * 4 + r;
      int c = h * 64 + t * 16 + l15;
      attb[((size_t)(n * S_ + q)) * C_ + c] = f2bf(acc[t][r]);
    }
}

// FC + residual: hp = x + att @ Wfc^T + bfc (fp32 out). R3 tile + swizzle.
__global__ __launch_bounds__(256) void k_fc(const u16* attb, const u16* Wfcb,
                                            const float* bfc, const float* x,
                                            float* hp) {
  __shared__ u16 As[64][72];
  __shared__ u16 Bs[64][72];
  int tid = threadIdx.x;
  int lin = blockIdx.x + 128 * blockIdx.y;  // 1024 blocks
  lin = (lin & 7) * (1024 >> 3) + (lin >> 3);
  int m0 = (lin & 127) * 64, n0 = (lin >> 7) * 64;
  int w = tid >> 6, lane = tid & 63, qd = lane >> 4, l15 = lane & 15;
  f32x4 acc[4] = {};
  for (int ks = 0; ks < 8; ++ks) {
    int k0 = ks * 64;
    __syncthreads();
    for (int u = tid; u < 512; u += 256) {
      int row = u >> 3, seg = u & 7;
      *(int4*)&As[row][seg * 8] =
          *(const int4*)&attb[(size_t)(m0 + row) * C_ + k0 + seg * 8];
      *(int4*)&Bs[row][seg * 8] =
          *(const int4*)&Wfcb[(size_t)(n0 + row) * C_ + k0 + seg * 8];
    }
    __syncthreads();
    for (int k2 = 0; k2 < 2; ++k2) {
      bf16x8 a = *(const bf16x8*)&As[w * 16 + l15][k2 * 32 + qd * 8];
      for (int t = 0; t < 4; ++t) {
        bf16x8 b = *(const bf16x8*)&Bs[t * 16 + l15][k2 * 32 + qd * 8];
        acc[t] = __builtin_amdgcn_mfma_f32_16x16x32_bf16(a, b, acc[t], 0, 0, 0);
      }
    }
  }
  for (int t = 0; t < 4; ++t)
    for (int r = 0; r < 4; ++r) {
      int m = m0 + w * 16 + qd * 4 + r;
      int c = n0 + t * 16 + l15;
      hp[(size_t)m * C_ + c] = acc[t][r] + bfc[c] + x[(size_t)m * C_ + c];
    }
}

// LayerNorm over C per row; fp32 in, bf16 out.
__global__ __launch_bounds__(512) void k_ln(const float* hp, const float* g,
                                            const float* b, u16* hb) {
  __shared__ float r1[8], r2[8];
  int row = blockIdx.x, tid = threadIdx.x;
  int w = tid >> 6, lane = tid & 63;
  float v = hp[(size_t)row * C_ + tid];
  float s1 = v, s2 = v * v;
  for (int m = 1; m < 64; m <<= 1) {
    s1 += __shfl_xor(s1, m, 64);
    s2 += __shfl_xor(s2, m, 64);
  }
  if (lane == 0) {
    r1[w] = s1;
    r2[w] = s2;
  }
  __syncthreads();
  float t1 = 0.f, t2 = 0.f;
  for (int i = 0; i < 8; ++i) {
    t1 += r1[i];
    t2 += r2[i];
  }
  float mu = t1 * (1.0f / C_);
  float var = t2 * (1.0f / C_) - mu * mu;
  float o = (v - mu) * rsqrtf(var + 1e-5f) * g[tid] + b[tid];
  hb[(size_t)row * C_ + tid] = f2bf(o);
}

// Causal conv (K=3, left pad 2) as 3 accumulated MFMA NT-GEMMs.
// R3 tile (s-tile 64, K-step 64) + XCD swizzle (chunk shares weight tile).
// mode 0: out = relu(acc+bias) -> outb bf16
// mode 1: out = relu(relu(acc+bias)+res) -> outf fp32
__global__ __launch_bounds__(256) void k_conv(const u16* in, const u16* wt,
                                              const float* bias,
                                              const u16* res, u16* outb,
                                              float* outf, int mode) {
  __shared__ u16 As[66][72];
  __shared__ u16 Bs[3][64][72];
  int tid = threadIdx.x;
  int lin = blockIdx.x + 128 * blockIdx.y;  // 1024 blocks
  lin = (lin & 7) * (1024 >> 3) + (lin >> 3);
  int m0 = (lin & 127) * 64, n0 = (lin >> 7) * 64;
  int n = m0 >> 10, s0 = m0 & 1023;
  int w = tid >> 6, lane = tid & 63, qd = lane >> 4, l15 = lane & 15;
  f32x4 acc[4] = {};
  for (int ks = 0; ks < 8; ++ks) {
    int k0 = ks * 64;
    __syncthreads();
    for (int u = tid; u < 528; u += 256) {
      int row = u >> 3, seg = u & 7;
      int s = s0 + row - 2;
      int4 pa;
      pa.x = pa.y = pa.z = pa.w = 0;
      if (s >= 0)
        pa = *(const int4*)&in[((size_t)(n * S_ + s)) * C_ + k0 + seg * 8];
      *(int4*)&As[row][seg * 8] = pa;
    }
    for (int u = tid; u < 1536; u += 256) {
      int tap = u >> 9, rr = (u >> 3) & 63, seg = u & 7;
      *(int4*)&Bs[tap][rr][seg * 8] = *(const int4*)&wt[
          (size_t)tap * C_ * C_ + (size_t)(n0 + rr) * C_ + k0 + seg * 8];
    }
    __syncthreads();
    for (int k2 = 0; k2 < 2; ++k2) {
      for (int tap = 0; tap < 3; ++tap) {
        bf16x8 a = *(const bf16x8*)&As[w * 16 + l15 + tap][k2 * 32 + qd * 8];
        for (int t = 0; t < 4; ++t) {
          bf16x8 b = *(const bf16x8*)&Bs[tap][t * 16 + l15][k2 * 32 + qd * 8];
          acc[t] =
              __builtin_amdgcn_mfma_f32_16x16x32_bf16(a, b, acc[t], 0, 0, 0);
        }
      }
    }
  }
  for (int t = 0; t < 4; ++t)
    for (int r = 0; r < 4; ++r) {
      int s = s0 + w * 16 + qd * 4 + r;
      int c = n0 + t * 16 + l15;
      float val = fmaxf(acc[t][r] + bias[c], 0.0f);
      size_t idx = ((size_t)(n * S_ + s)) * C_ + c;
      if (mode) {
        val = fmaxf(val + bf2f(res[idx]), 0.0f);
        outf[idx] = val;
      } else {
        outb[idx] = f2bf(val);
      }
    }
}

extern "C" void kernel_launch(void* const* d_in, const int* in_sizes, int n_in,
                              void* d_out, int out_size, void* d_ws,
                              size_t ws_size, hipStream_t stream) {
  int o = (in_sizes[1] == D_ * D_) ? 1 : 2;  // dict vs signature order
  const float* x = (const float*)d_in[0];
  const float* Wq = (const float*)d_in[o + 0];
  const float* Wk = (const float*)d_in[o + 1];
  const float* Wv = (const float*)d_in[o + 2];
  const float* Wfc = (const float*)d_in[o + 3];
  const float* bfc = (const float*)d_in[o + 4];
  const float* Wpre = (const float*)d_in[o + 5];
  const float* Wpost = (const float*)d_in[o + 6];
  const float* pk = (const float*)d_in[o + 7];
  const float* pv = (const float*)d_in[o + 8];
  const float* lng = (const float*)d_in[o + 9];
  const float* lnb = (const float*)d_in[o + 10];
  const float* c1w = (const float*)d_in[o + 11];
  const float* c1b = (const float*)d_in[o + 12];
  const float* c2w = (const float*)d_in[o + 13];
  const float* c2b = (const float*)d_in[o + 14];
  float* out = (float*)d_out;

  // Workspace ~232 MB (ws_size = 256 MiB per the harness poison fill).
  char* ws = (char*)d_ws;
  size_t off = 0;
  u16* qb = (u16*)(ws + off);   off += (size_t)B_ * H_ * S_ * D_ * 2;
  u16* kb = (u16*)(ws + off);   off += (size_t)B_ * H_ * SPAD_ * D_ * 2;
  u16* vb = (u16*)(ws + off);   off += (size_t)B_ * H_ * SPAD_ * D_ * 2;
  u16* vtb = (u16*)(ws + off);  off += (size_t)B_ * H_ * D_ * SPAD_ * 2;
  u16* Sb = (u16*)(ws + off);   off += (size_t)B_ * H_ * S_ * SPAD_ * 2;  // 142.6MB
  u16* attb = (u16*)(ws + off); off += (size_t)B_ * S_ * C_ * 2;
  float* hp = (float*)(ws + off); off += (size_t)B_ * S_ * C_ * 4;
  u16* hb = (u16*)(ws + off);   off += (size_t)B_ * S_ * C_ * 2;
  u16* o1b = (u16*)(ws + off);  off += (size_t)B_ * S_ * C_ * 2;
  u16* wfcb = (u16*)(ws + off); off += (size_t)C_ * C_ * 2;
  u16* w1t = (u16*)(ws + off);  off += (size_t)KSZ * C_ * C_ * 2;
  u16* w2t = (u16*)(ws + off);  off += (size_t)KSZ * C_ * C_ * 2;
  u16* xb = (u16*)(ws + off);   off += (size_t)B_ * S_ * C_ * 2;

  k_prep<<<7168, 256, 0, stream>>>(Wfc, wfcb, c1w, w1t, c2w, w2t);
  k_xcvt<<<2048, 256, 0, stream>>>(x, xb);
  k_qkv<<<dim3(128, 24), 256, 0, stream>>>(xb, Wq, Wk, Wv, qb, kb, vb);
  k_prefix<<<1024, 256, 0, stream>>>(pk, pv, kb, vb);
  k_vtrans<<<dim3(17, 64), 256, 0, stream>>>(vb, vtb);
  k_energy<<<dim3(17, 16, 64), 256, 0, stream>>>(qb, kb, Sb);
  k_smx<<<8192, 256, 0, stream>>>(Sb, Wpre, Wpost);
  k_av<<<dim3(16, 64), 256, 0, stream>>>(Sb, vtb, attb);
  k_fc<<<dim3(128, 8), 256, 0, stream>>>(attb, wfcb, bfc, x, hp);
  k_ln<<<8192, 512, 0, stream>>>(hp, lng, lnb, hb);
  k_conv<<<dim3(128, 8), 256, 0, stream>>>(hb, w1t, c1b, (const u16*)0, o1b,
                                           (float*)0, 0);
  k_conv<<<dim3(128, 8), 256, 0, stream>>>(o1b, w2t, c2b, hb, (u16*)0, out, 1);
}

// Round 6
// 336.571 us; speedup vs baseline: 1.1974x; 1.0137x over previous
//
#include <hip/hip_runtime.h>

#define B_ 8
#define S_ 1024
#define C_ 512
#define H_ 8
#define D_ 64
#define P_ 16
#define SP_ 1040    // valid keys: S + P
#define SPAD_ 1088  // score-matrix row stride: 17*64
#define KSZ 3

typedef unsigned short u16;
typedef short bf16x8 __attribute__((ext_vector_type(8)));
typedef float f32x4 __attribute__((ext_vector_type(4)));

__device__ __forceinline__ float bf2f(u16 u) {
  return __uint_as_float(((unsigned int)u) << 16);
}
__device__ __forceinline__ u16 f2bf(float f) {
  unsigned int u = __float_as_uint(f);
  return (u16)((u + 0x7fffu + ((u >> 16) & 1u)) >> 16);
}
// Packed fp32->bf16 RNE convert: 1 instr for 2 values (same rounding as f2bf).
__device__ __forceinline__ unsigned int cvtpk(float lo, float hi) {
  unsigned int r;
  asm("v_cvt_pk_bf16_f32 %0, %1, %2" : "=v"(r) : "v"(lo), "v"(hi));
  return r;
}
// Raw v_exp_f32: computes 2^x in one instruction.
__device__ __forceinline__ float exp2v(float x) {
  float r;
  asm("v_exp_f32 %0, %1" : "=v"(r) : "v"(x));
  return r;
}
// Round 8 consecutive fp32 to bf16, packed as int4 (8 x u16).
__device__ __forceinline__ int4 pack8(const float* p) {
  int4 r;
  r.x = (int)cvtpk(p[0], p[1]);
  r.y = (int)cvtpk(p[2], p[3]);
  r.z = (int)cvtpk(p[4], p[5]);
  r.w = (int)cvtpk(p[6], p[7]);
  return r;
}

// Merged prep: x cvt | Wfc cvt + conv repacks | k/v prefix | Wq/Wk/Wv cvt.
// Range-dispatched on blockIdx: [0,2048) xcvt, [2048,9216) weights,
// [9216,10240) prefix, [10240,10288) qkv weights.
__global__ void k_prep(const float* x, u16* xb, const float* Wfc, u16* wfcb,
                       const float* c1w, u16* w1t, const float* c2w, u16* w2t,
                       const float* Wq, const float* Wk, const float* Wv,
                       u16* wb3, const float* pk, const float* pv, u16* kb,
                       u16* vtb) {
  int b = blockIdx.x, tid = threadIdx.x;
  if (b < 2048) {  // x fp32 -> bf16, 8 elems/thread
    int gid = b * 256 + tid;
    *(int4*)&xb[(size_t)gid * 8] = pack8(&x[(size_t)gid * 8]);
    return;
  }
  if (b < 9216) {  // Wfc cvt + conv1/conv2 repack
    int gid = (b - 2048) * 256 + tid;
    if (gid < C_ * C_) {
      wfcb[gid] = f2bf(Wfc[gid]);
      return;
    }
    int r = gid - C_ * C_;
    const float* src = c1w;
    u16* dst = w1t;
    if (r >= C_ * C_ * KSZ) {
      r -= C_ * C_ * KSZ;
      src = c2w;
      dst = w2t;
    }
    int co = r / (C_ * KSZ);
    int rem = r - co * (C_ * KSZ);
    int ci = rem / KSZ;
    int tap = rem - ci * KSZ;
    dst[(size_t)tap * C_ * C_ + co * C_ + ci] = f2bf(src[r]);
    return;
  }
  if (b < 10240) {  // prefix rows: kb[S..SPAD) + vtb[.., 1024..1088)
    int g = (b - 9216) * 256 + tid;  // 262144
    {
      int d = g & 63, t = g >> 6, p = t & 63, nh = t >> 6;
      kb[((size_t)nh * SPAD_ + S_ + p) * D_ + d] =
          (p < P_) ? f2bf(pk[p * 64 + d]) : 0;
    }
    {
      int p = g & 63, d = (g >> 6) & 63, nh = g >> 12;
      vtb[((size_t)nh * D_ + d) * SPAD_ + S_ + p] =
          (p < P_) ? f2bf(pv[p * 64 + d]) : 0;
    }
    return;
  }
  {  // Wq/Wk/Wv -> bf16 wb3[mat][64][64]
    int e = (b - 10240) * 256 + tid;  // 12288
    int mat = e >> 12, idx = e & 4095;
    const float* W = (mat == 0) ? Wq : ((mat == 1) ? Wk : Wv);
    wb3[e] = f2bf(W[idx]);
  }
}

// QKV: per (mat, head) NT-GEMM via MFMA, M=B*S, N=64, K=64.
// R6: W pre-converted (wb3); V written directly transposed to vtb via LDS
// bounce (k_vtrans removed). XCD-chunked swizzle (R5).
__global__ __launch_bounds__(256) void k_qkv(
    const u16* xb, const u16* wb3, u16* qb, u16* kb, u16* vtb) {
  __shared__ u16 As[64][72];
  __shared__ u16 Bs[64][72];
  int tid = threadIdx.x;
  int lin = blockIdx.x + 128 * blockIdx.y;        // 3072 blocks
  lin = (lin & 7) * (3072 >> 3) + (lin >> 3);     // bijective XCD chunking
  int m0 = (lin / 24) * 64;
  int yy = lin % 24;
  int mat = yy >> 3, h = yy & 7;
  for (int u = tid; u < 512; u += 256) {
    int row = u >> 3, seg = u & 7;
    *(int4*)&As[row][seg * 8] =
        *(const int4*)&xb[(size_t)(m0 + row) * C_ + h * 64 + seg * 8];
    *(int4*)&Bs[row][seg * 8] =
        *(const int4*)&wb3[(mat << 12) + row * 64 + seg * 8];
  }
  __syncthreads();
  int w = tid >> 6, lane = tid & 63, qd = lane >> 4, l15 = lane & 15;
  f32x4 acc[4] = {};
  for (int ks = 0; ks < 2; ++ks) {
    bf16x8 a = *(const bf16x8*)&As[w * 16 + l15][ks * 32 + qd * 8];
    for (int t = 0; t < 4; ++t) {
      bf16x8 b = *(const bf16x8*)&Bs[t * 16 + l15][ks * 32 + qd * 8];
      acc[t] = __builtin_amdgcn_mfma_f32_16x16x32_bf16(a, b, acc[t], 0, 0, 0);
    }
  }
  int n = m0 >> 10, s0 = m0 & 1023;
  if (mat == 2) {
    // transpose in LDS: As[d][s_local] then coalesced store to vtb[nh][d][s].
    __syncthreads();
    for (int t = 0; t < 4; ++t)
      for (int r = 0; r < 4; ++r)
        As[t * 16 + l15][w * 16 + qd * 4 + r] = f2bf(acc[t][r]);
    __syncthreads();
    int nh = n * H_ + h;
    for (int u = tid; u < 512; u += 256) {
      int d = u >> 3, seg = u & 7;
      *(int4*)&vtb[((size_t)nh * D_ + d) * SPAD_ + s0 + seg * 8] =
          *(const int4*)&As[d][seg * 8];
    }
    return;
  }
  for (int t = 0; t < 4; ++t)
    for (int r = 0; r < 4; ++r) {
      int s = s0 + w * 16 + qd * 4 + r;
      int d = t * 16 + l15;
      u16 val = f2bf(acc[t][r]);
      if (mat == 0)
        qb[((size_t)(n * H_ + h) * S_ + s) * D_ + d] = val;
      else
        kb[((size_t)(n * H_ + h) * SPAD_ + s) * D_ + d] = val;
    }
}

// Energy: Sb[nh][q][l] = q.k via MFMA (R3 64-tile + R5 XCD swizzle).
__global__ __launch_bounds__(256) void k_energy(const u16* qb, const u16* kb,
                                                u16* Sb) {
  __shared__ u16 As[64][72];
  __shared__ u16 Bs[64][72];
  int tid = threadIdx.x;
  int lin = blockIdx.x + 17 * (blockIdx.y + 16 * blockIdx.z);  // 17408
  lin = (lin & 7) * (17408 >> 3) + (lin >> 3);
  int l0 = (lin % 17) * 64;
  int t0 = lin / 17;
  int q0 = (t0 & 15) * 64;
  int nh = t0 >> 4;  // n*H + h
  const u16* qsrc = qb + ((size_t)nh * S_ + q0) * D_;
  const u16* ksrc = kb + ((size_t)nh * SPAD_ + l0) * D_;
  for (int u = tid; u < 512; u += 256) {
    int row = u >> 3, seg = u & 7;
    *(int4*)&As[row][seg * 8] = *(const int4*)&qsrc[row * 64 + seg * 8];
    *(int4*)&Bs[row][seg * 8] = *(const int4*)&ksrc[row * 64 + seg * 8];
  }
  __syncthreads();
  int w = tid >> 6, lane = tid & 63, qd = lane >> 4, l15 = lane & 15;
  f32x4 acc[4] = {};
  for (int ks = 0; ks < 2; ++ks) {
    bf16x8 a = *(const bf16x8*)&As[w * 16 + l15][ks * 32 + qd * 8];
    for (int t = 0; t < 4; ++t) {
      bf16x8 b = *(const bf16x8*)&Bs[t * 16 + l15][ks * 32 + qd * 8];
      acc[t] = __builtin_amdgcn_mfma_f32_16x16x32_bf16(a, b, acc[t], 0, 0, 0);
    }
  }
  for (int t = 0; t < 4; ++t)
    for (int r = 0; r < 4; ++r) {
      int q = q0 + w * 16 + qd * 4 + r;
      int l = l0 + t * 16 + l15;
      Sb[((size_t)nh * S_ + q) * SPAD_ + l] = f2bf(acc[t][r]);
    }
}

// Per (n,q): premix (W_pre + folded ALiBi), softmax over l<SP, postmix.
// R6: NO max pass -- softmax shift-invariance means exp2 of the raw scaled
// energy is mathematically identical; range is bounded (max ~ +3 in exp2
// domain, min > -50) so no overflow/underflow. Saves the fmax chain, one
// butterfly+LDS reduction round, two barriers, and 40 subtracts.
__global__ __launch_bounds__(256) void k_smx(u16* __restrict__ Sb,
                                             const float* __restrict__ Wpre,
                                             const float* __restrict__ Wpost) {
  __shared__ __align__(16) float red[8][36];  // [head][group], 32 groups
  __shared__ __align__(16) float izf[8];      // 1/sum per head
  int tid = threadIdx.x;
  int n = blockIdx.x >> 10, q = blockIdx.x & 1023;
  const size_t hs = (size_t)S_ * SPAD_;
  u16* __restrict__ base = Sb + ((size_t)n * H_ * S_ + q) * SPAD_;
  // 1/sqrt(512) * log2(e): softmax in exp2 domain (exact same math).
  const float isc2 = 0.04419417382415922f * 1.4426950408889634f;

  int la = 4 * tid;
  bool hasB = (tid < 16);
  int lb = 1024 + tid;  // 16 valid prefix keys

  // Issue all global loads up front (MLP).
  uint2 ldA[8];
#pragma unroll
  for (int i = 0; i < 8; ++i) ldA[i] = *(const uint2*)(base + i * hs + la);
  u16 ldB[8];
  if (hasB) {
#pragma unroll
    for (int i = 0; i < 8; ++i) ldB[i] = base[i * hs + lb];
  }

  float bt[4];
#pragma unroll
  for (int j = 0; j < 4; ++j) bt[j] = -fabsf((float)(q - (la + j)));

  // ---------- premix chunk A (bias folded into inputs) ----------
  float eA[32];  // [o][4]
#pragma unroll
  for (int j = 0; j < 32; ++j) eA[j] = 0.f;
#pragma unroll
  for (int i = 0; i < 8; ++i) {
    const float ci = 1.0f / (float)(2 << i);  // 2^-(i+1), compile-time
    float x0 = bf2f((u16)(ldA[i].x & 0xffffu)) + bt[0] * ci;
    float x1 = bf2f((u16)(ldA[i].x >> 16)) + bt[1] * ci;
    float x2 = bf2f((u16)(ldA[i].y & 0xffffu)) + bt[2] * ci;
    float x3 = bf2f((u16)(ldA[i].y >> 16)) + bt[3] * ci;
#pragma unroll
    for (int o = 0; o < 8; ++o) {
      float wv = Wpre[o * 8 + i];  // uniform -> s_load, SGPR operand
      eA[4 * o + 0] += wv * x0;
      eA[4 * o + 1] += wv * x1;
      eA[4 * o + 2] += wv * x2;
      eA[4 * o + 3] += wv * x3;
    }
  }

  // ---------- premix tail: 16 prefix keys, 1 per thread, no bias ----------
  float eB[8];
  if (hasB) {
#pragma unroll
    for (int o = 0; o < 8; ++o) eB[o] = 0.f;
#pragma unroll
    for (int i = 0; i < 8; ++i) {
      float xi = bf2f(ldB[i]);
#pragma unroll
      for (int o = 0; o < 8; ++o) eB[o] += Wpre[o * 8 + i] * xi;
    }
  }

  // ---------- exp2 (no shift) + block-wide sum ----------
  float zl[8];
#pragma unroll
  for (int o = 0; o < 8; ++o) {
    float s = 0.f;
#pragma unroll
    for (int j = 0; j < 4; ++j) {
      eA[4 * o + j] = exp2v(eA[4 * o + j] * isc2);
      s += eA[4 * o + j];
    }
    zl[o] = s;
  }
  if (hasB) {
#pragma unroll
    for (int o = 0; o < 8; ++o) {
      eB[o] = exp2v(eB[o] * isc2);
      zl[o] += eB[o];
    }
  }
#pragma unroll
  for (int o = 0; o < 8; ++o)
    for (int mm = 1; mm < 8; mm <<= 1) zl[o] += __shfl_xor(zl[o], mm, 64);
  {
    int g = tid >> 3;
    if ((tid & 7) == 0) {
#pragma unroll
      for (int o = 0; o < 8; ++o) red[o][g] = zl[o];
    }
  }
  __syncthreads();
  if (tid < 64) {
    int o = tid >> 3, part = tid & 7;
    f32x4 pv = *(const f32x4*)&red[o][part * 4];
    float ps = (pv[0] + pv[1]) + (pv[2] + pv[3]);
    for (int mm = 1; mm < 8; mm <<= 1) ps += __shfl_xor(ps, mm, 64);
    if (part == 0) izf[o] = 1.0f / ps;
  }
  __syncthreads();

  f32x4 zlo = *(const f32x4*)&izf[0];
  f32x4 zhi = *(const f32x4*)&izf[4];

  // ---------- normalize + postmix + store, chunk A ----------
  {
#pragma unroll
    for (int o = 0; o < 8; ++o) {
      float iz = (o < 4) ? zlo[o & 3] : zhi[o & 3];
#pragma unroll
      for (int j = 0; j < 4; ++j) eA[4 * o + j] *= iz;
    }
#pragma unroll
    for (int o = 0; o < 8; ++o) {
      float p0 = 0.f, p1 = 0.f, p2 = 0.f, p3 = 0.f;
#pragma unroll
      for (int i = 0; i < 8; ++i) {
        float wv = Wpost[o * 8 + i];  // uniform -> s_load
        p0 += wv * eA[4 * i + 0];
        p1 += wv * eA[4 * i + 1];
        p2 += wv * eA[4 * i + 2];
        p3 += wv * eA[4 * i + 3];
      }
      uint2 u;
      u.x = cvtpk(p0, p1);
      u.y = cvtpk(p2, p3);
      *(uint2*)(base + o * hs + la) = u;
    }
  }
  // ---------- normalize + postmix + store, tail ----------
  if (hasB) {
#pragma unroll
    for (int o = 0; o < 8; ++o) {
      float iz = (o < 4) ? zlo[o & 3] : zhi[o & 3];
      eB[o] *= iz;
    }
#pragma unroll
    for (int o = 0; o < 8; ++o) {
      float p0 = 0.f;
#pragma unroll
      for (int i = 0; i < 8; ++i) p0 += Wpost[o * 8 + i] * eB[i];
      base[o * hs + lb] = f2bf(p0);
    }
  }
}

// AV: attb = attn @ vT (R3 64-tile, K-step 64, R5 XCD swizzle).
__global__ __launch_bounds__(256) void k_av(const u16* Sb, const u16* vtb,
                                            u16* attb) {
  __shared__ u16 As[64][72];
  __shared__ u16 Bs[64][72];
  int tid = threadIdx.x;
  int lin = blockIdx.x + 16 * blockIdx.y;  // 1024 blocks
  lin = (lin & 7) * (1024 >> 3) + (lin >> 3);
  int q0 = (lin & 15) * 64;
  int nh = lin >> 4;
  int n = nh >> 3, h = nh & 7;
  const u16* Ab = Sb + ((size_t)nh * S_ + q0) * SPAD_;
  const u16* Bb = vtb + (size_t)nh * D_ * SPAD_;
  int w = tid >> 6, lane = tid & 63, qd = lane >> 4, l15 = lane & 15;
  f32x4 acc[4] = {};
  for (int ks = 0; ks < 17; ++ks) {
    int k0 = ks * 64;
    __syncthreads();
    for (int u = tid; u < 512; u += 256) {
      int row = u >> 3, seg = u & 7;
      *(int4*)&As[row][seg * 8] =
          *(const int4*)&Ab[(size_t)row * SPAD_ + k0 + seg * 8];
      *(int4*)&Bs[row][seg * 8] =
          *(const int4*)&Bb[(size_t)row * SPAD_ + k0 + seg * 8];
    }
    __syncthreads();
    for (int k2 = 0; k2 < 2; ++k2) {
      bf16x8 a = *(const bf16x8*)&As[w * 16 + l15][k2 * 32 + qd * 8];
      for (int t = 0; t < 4; ++t) {
        bf16x8 b = *(const bf16x8*)&Bs[t * 16 + l15][k2 * 32 + qd * 8];
        acc[t] = __builtin_amdgcn_mfma_f32_16x16x32_bf16(a, b, acc[t], 0, 0, 0);
      }
    }
  }
  for (int t = 0; t < 4; ++t)
    for (int r = 0; r < 4; ++r) {
      int q = q0 + w * 16 + qd * 4 + r;
      int c = h * 64 + t * 16 + l15;
      attb[((size_t)(n * S_ + q)) * C_ + c] = f2bf(acc[t][r]);
    }
}

// FC + residual: hp = x + att @ Wfc^T + bfc (fp32 out). R3 tile + swizzle.
__global__ __launch_bounds__(256) void k_fc(const u16* attb, const u16* Wfcb,
                                            const float* bfc, const float* x,
                                            float* hp) {
  __shared__ u16 As[64][72];
  __shared__ u16 Bs[64][72];
  int tid = threadIdx.x;
  int lin = blockIdx.x + 128 * blockIdx.y;  // 1024 blocks
  lin = (lin & 7) * (1024 >> 3) + (lin >> 3);
  int m0 = (lin & 127) * 64, n0 = (lin >> 7) * 64;
  int w = tid >> 6, lane = tid & 63, qd = lane >> 4, l15 = lane & 15;
  f32x4 acc[4] = {};
  for (int ks = 0; ks < 8; ++ks) {
    int k0 = ks * 64;
    __syncthreads();
    for (int u = tid; u < 512; u += 256) {
      int row = u >> 3, seg = u & 7;
      *(int4*)&As[row][seg * 8] =
          *(const int4*)&attb[(size_t)(m0 + row) * C_ + k0 + seg * 8];
      *(int4*)&Bs[row][seg * 8] =
          *(const int4*)&Wfcb[(size_t)(n0 + row) * C_ + k0 + seg * 8];
    }
    __syncthreads();
    for (int k2 = 0; k2 < 2; ++k2) {
      bf16x8 a = *(const bf16x8*)&As[w * 16 + l15][k2 * 32 + qd * 8];
      for (int t = 0; t < 4; ++t) {
        bf16x8 b = *(const bf16x8*)&Bs[t * 16 + l15][k2 * 32 + qd * 8];
        acc[t] = __builtin_amdgcn_mfma_f32_16x16x32_bf16(a, b, acc[t], 0, 0, 0);
      }
    }
  }
  for (int t = 0; t < 4; ++t)
    for (int r = 0; r < 4; ++r) {
      int m = m0 + w * 16 + qd * 4 + r;
      int c = n0 + t * 16 + l15;
      hp[(size_t)m * C_ + c] = acc[t][r] + bfc[c] + x[(size_t)m * C_ + c];
    }
}

// LayerNorm over C per row; fp32 in, bf16 out.
__global__ __launch_bounds__(512) void k_ln(const float* hp, const float* g,
                                            const float* b, u16* hb) {
  __shared__ float r1[8], r2[8];
  int row = blockIdx.x, tid = threadIdx.x;
  int w = tid >> 6, lane = tid & 63;
  float v = hp[(size_t)row * C_ + tid];
  float s1 = v, s2 = v * v;
  for (int m = 1; m < 64; m <<= 1) {
    s1 += __shfl_xor(s1, m, 64);
    s2 += __shfl_xor(s2, m, 64);
  }
  if (lane == 0) {
    r1[w] = s1;
    r2[w] = s2;
  }
  __syncthreads();
  float t1 = 0.f, t2 = 0.f;
  for (int i = 0; i < 8; ++i) {
    t1 += r1[i];
    t2 += r2[i];
  }
  float mu = t1 * (1.0f / C_);
  float var = t2 * (1.0f / C_) - mu * mu;
  float o = (v - mu) * rsqrtf(var + 1e-5f) * g[tid] + b[tid];
  hb[(size_t)row * C_ + tid] = f2bf(o);
}

// Causal conv (K=3, left pad 2) as 3 accumulated MFMA NT-GEMMs.
// R3 tile (s-tile 64, K-step 64) + XCD swizzle (chunk shares weight tile).
// mode 0: out = relu(acc+bias) -> outb bf16
// mode 1: out = relu(relu(acc+bias)+res) -> outf fp32
__global__ __launch_bounds__(256) void k_conv(const u16* in, const u16* wt,
                                              const float* bias,
                                              const u16* res, u16* outb,
                                              float* outf, int mode) {
  __shared__ u16 As[66][72];
  __shared__ u16 Bs[3][64][72];
  int tid = threadIdx.x;
  int lin = blockIdx.x + 128 * blockIdx.y;  // 1024 blocks
  lin = (lin & 7) * (1024 >> 3) + (lin >> 3);
  int m0 = (lin & 127) * 64, n0 = (lin >> 7) * 64;
  int n = m0 >> 10, s0 = m0 & 1023;
  int w = tid >> 6, lane = tid & 63, qd = lane >> 4, l15 = lane & 15;
  f32x4 acc[4] = {};
  for (int ks = 0; ks < 8; ++ks) {
    int k0 = ks * 64;
    __syncthreads();
    for (int u = tid; u < 528; u += 256) {
      int row = u >> 3, seg = u & 7;
      int s = s0 + row - 2;
      int4 pa;
      pa.x = pa.y = pa.z = pa.w = 0;
      if (s >= 0)
        pa = *(const int4*)&in[((size_t)(n * S_ + s)) * C_ + k0 + seg * 8];
      *(int4*)&As[row][seg * 8] = pa;
    }
    for (int u = tid; u < 1536; u += 256) {
      int tap = u >> 9, rr = (u >> 3) & 63, seg = u & 7;
      *(int4*)&Bs[tap][rr][seg * 8] = *(const int4*)&wt[
          (size_t)tap * C_ * C_ + (size_t)(n0 + rr) * C_ + k0 + seg * 8];
    }
    __syncthreads();
    for (int k2 = 0; k2 < 2; ++k2) {
      for (int tap = 0; tap < 3; ++tap) {
        bf16x8 a = *(const bf16x8*)&As[w * 16 + l15 + tap][k2 * 32 + qd * 8];
        for (int t = 0; t < 4; ++t) {
          bf16x8 b = *(const bf16x8*)&Bs[tap][t * 16 + l15][k2 * 32 + qd * 8];
          acc[t] =
              __builtin_amdgcn_mfma_f32_16x16x32_bf16(a, b, acc[t], 0, 0, 0);
        }
      }
    }
  }
  for (int t = 0; t < 4; ++t)
    for (int r = 0; r < 4; ++r) {
      int s = s0 + w * 16 + qd * 4 + r;
      int c = n0 + t * 16 + l15;
      float val = fmaxf(acc[t][r] + bias[c], 0.0f);
      size_t idx = ((size_t)(n * S_ + s)) * C_ + c;
      if (mode) {
        val = fmaxf(val + bf2f(res[idx]), 0.0f);
        outf[idx] = val;
      } else {
        outb[idx] = f2bf(val);
      }
    }
}

extern "C" void kernel_launch(void* const* d_in, const int* in_sizes, int n_in,
                              void* d_out, int out_size, void* d_ws,
                              size_t ws_size, hipStream_t stream) {
  int o = (in_sizes[1] == D_ * D_) ? 1 : 2;  // dict vs signature order
  const float* x = (const float*)d_in[0];
  const float* Wq = (const float*)d_in[o + 0];
  const float* Wk = (const float*)d_in[o + 1];
  const float* Wv = (const float*)d_in[o + 2];
  const float* Wfc = (const float*)d_in[o + 3];
  const float* bfc = (const float*)d_in[o + 4];
  const float* Wpre = (const float*)d_in[o + 5];
  const float* Wpost = (const float*)d_in[o + 6];
  const float* pk = (const float*)d_in[o + 7];
  const float* pv = (const float*)d_in[o + 8];
  const float* lng = (const float*)d_in[o + 9];
  const float* lnb = (const float*)d_in[o + 10];
  const float* c1w = (const float*)d_in[o + 11];
  const float* c1b = (const float*)d_in[o + 12];
  const float* c2w = (const float*)d_in[o + 13];
  const float* c2b = (const float*)d_in[o + 14];
  float* out = (float*)d_out;

  // Workspace ~215 MB (ws_size = 256 MiB per the harness poison fill).
  char* ws = (char*)d_ws;
  size_t off = 0;
  u16* qb = (u16*)(ws + off);   off += (size_t)B_ * H_ * S_ * D_ * 2;
  u16* kb = (u16*)(ws + off);   off += (size_t)B_ * H_ * SPAD_ * D_ * 2;
  u16* vtb = (u16*)(ws + off);  off += (size_t)B_ * H_ * D_ * SPAD_ * 2;
  u16* Sb = (u16*)(ws + off);   off += (size_t)B_ * H_ * S_ * SPAD_ * 2;  // 142.6MB
  u16* attb = (u16*)(ws + off); off += (size_t)B_ * S_ * C_ * 2;
  float* hp = (float*)(ws + off); off += (size_t)B_ * S_ * C_ * 4;
  u16* hb = (u16*)(ws + off);   off += (size_t)B_ * S_ * C_ * 2;
  u16* o1b = (u16*)(ws + off);  off += (size_t)B_ * S_ * C_ * 2;
  u16* wfcb = (u16*)(ws + off); off += (size_t)C_ * C_ * 2;
  u16* w1t = (u16*)(ws + off);  off += (size_t)KSZ * C_ * C_ * 2;
  u16* w2t = (u16*)(ws + off);  off += (size_t)KSZ * C_ * C_ * 2;
  u16* xb = (u16*)(ws + off);   off += (size_t)B_ * S_ * C_ * 2;
  u16* wb3 = (u16*)(ws + off);  off += (size_t)3 * D_ * D_ * 2;

  k_prep<<<10288, 256, 0, stream>>>(x, xb, Wfc, wfcb, c1w, w1t, c2w, w2t,
                                    Wq, Wk, Wv, wb3, pk, pv, kb, vtb);
  k_qkv<<<dim3(128, 24), 256, 0, stream>>>(xb, wb3, qb, kb, vtb);
  k_energy<<<dim3(17, 16, 64), 256, 0, stream>>>(qb, kb, Sb);
  k_smx<<<8192, 256, 0, stream>>>(Sb, Wpre, Wpost);
  k_av<<<dim3(16, 64), 256, 0, stream>>>(Sb, vtb, attb);
  k_fc<<<dim3(128, 8), 256, 0, stream>>>(attb, wfcb, bfc, x, hp);
  k_ln<<<8192, 512, 0, stream>>>(hp, lng, lnb, hb);
  k_conv<<<dim3(128, 8), 256, 0, stream>>>(hb, w1t, c1b, (const u16*)0, o1b,
                                           (float*)0, 0);
  k_conv<<<dim3(128, 8), 256, 0, stream>>>(o1b, w2t, c2b, hb, (u16*)0, out, 1);
}